// Round 2
// baseline (382.722 us; speedup 1.0000x reference)
//
#include <hip/hip_runtime.h>
#include <cstdint>

// ---------------------------------------------------------------------------
// T-LSTM cell, fp32 in/out, 3-pass split-bf16 MFMA.
// Round 6: 4-phase interleaved K-step (m201/T3 style). Same BM=256 x BN=128,
// BK=32, 8 waves (4Mx2N, 64x64/wave), double-buffered LDS, counted vmcnt.
// Each K-step is split by C-quadrant:
//   P0: [stage next tile, vmcnt(6)] bar; read A01+B01; 12 MFMA (q00); bar
//   P1: read B23; 12 MFMA (q01); bar
//   P2: read A23; 12 MFMA (q11); bar
//   P3: (no reads, operands live) 12 MFMA (q10); bar
// Fast waves issue next phase's ds_reads while laggards finish MFMAs ->
// LDS-port time hides under MFMA time (R5's monolithic step serialized them:
// 1540cy LDS + 1860cy MFMA = 3765cy/step measured).
// ---------------------------------------------------------------------------

typedef __attribute__((ext_vector_type(8))) __bf16 bf16x8;
typedef __attribute__((ext_vector_type(4))) float f32x4;

__device__ __forceinline__ unsigned short f2bf_rn(float f) {
  unsigned int u = __float_as_uint(f);
  unsigned int r = u + 0x7fffu + ((u >> 16) & 1u);
  return (unsigned short)(r >> 16);
}
__device__ __forceinline__ float bf2f(unsigned short h) {
  return __uint_as_float(((unsigned int)h) << 16);
}
__device__ __forceinline__ float sigm_f(float x) {
  return 1.0f / (1.0f + __expf(-x));
}
__device__ __forceinline__ float tanh_f(float x) {
  return 1.0f - 2.0f / (__expf(2.0f * x) + 1.0f);
}
__device__ __forceinline__ void gl_lds16(const void* g, void* l) {
  __builtin_amdgcn_global_load_lds(
      (const __attribute__((address_space(1))) void*)g,
      (__attribute__((address_space(3))) void*)l, 16, 0, 0);
}

// --- prep: split X=[input|hx], W=[w_ih|w_hh] (rows gate-interleaved), cx.
__global__ __launch_bounds__(384) void prep_k(
    const float* __restrict__ input, const float* __restrict__ hx,
    const float* __restrict__ w_ih, const float* __restrict__ w_hh,
    const float* __restrict__ cx,
    unsigned short* __restrict__ Xhi, unsigned short* __restrict__ Xlo,
    unsigned short* __restrict__ Whi, unsigned short* __restrict__ Wlo,
    unsigned short* __restrict__ Chi, unsigned short* __restrict__ Clo) {
  const int bid = blockIdx.x;
  const int k = threadIdx.x << 2;
  const float* src;
  unsigned short *hi, *lo;
  if (bid < 4096) {
    const long m = bid;
    src = (k < 512) ? (input + m * 512 + k) : (hx + m * 1024 + (k - 512));
    hi = Xhi + m * 1536 + k;
    lo = Xlo + m * 1536 + k;
  } else if (bid < 8192) {
    const int n = bid - 4096;
    const int g = n >> 10;
    const int h = n & 1023;
    const long nd = ((long)(h >> 4) << 6) | (g << 4) | (h & 15);  // 16-h interleave
    src = (k < 512) ? (w_ih + (long)n * 512 + k) : (w_hh + (long)n * 1024 + (k - 512));
    hi = Whi + nd * 1536 + k;
    lo = Wlo + nd * 1536 + k;
  } else {
    if (k >= 1024) return;
    const long m = bid - 8192;
    src = cx + m * 1024 + k;
    hi = Chi + m * 1024 + k;
    lo = Clo + m * 1024 + k;
  }
  float4 v = *(const float4*)src;
  ushort4 hv, lv;
  hv.x = f2bf_rn(v.x); lv.x = f2bf_rn(v.x - bf2f(hv.x));
  hv.y = f2bf_rn(v.y); lv.y = f2bf_rn(v.y - bf2f(hv.y));
  hv.z = f2bf_rn(v.z); lv.z = f2bf_rn(v.z - bf2f(hv.z));
  hv.w = f2bf_rn(v.w); lv.w = f2bf_rn(v.w - bf2f(hv.w));
  *(ushort4*)hi = hv;
  *(ushort4*)lo = lv;
}

// --- transpose-split W_decomp [K,H] fp32 -> D[h][k]=W[k][h] hi/lo bf16
__global__ void transpose_split_k(const float* __restrict__ W, int Ndim,
                                  unsigned short* __restrict__ Thi,
                                  unsigned short* __restrict__ Tlo) {
  __shared__ float tile[64][65];
  const int bx = blockIdx.x * 64;
  const int by = blockIdx.y * 64;
  const int tx = threadIdx.x;
  for (int r = threadIdx.y; r < 64; r += 4)
    tile[r][tx] = W[(long)(by + r) * Ndim + bx + tx];
  __syncthreads();
  for (int r = threadIdx.y; r < 64; r += 4) {
    float v = tile[tx][r];  // = W[by+tx][bx+r]
    unsigned short h = f2bf_rn(v);
    long o = (long)(bx + r) * Ndim + by + tx;
    Thi[o] = h;
    Tlo[o] = f2bf_rn(v - bf2f(h));
  }
}

// --- mega kernel, 4-phase pipelined.
__global__ __launch_bounds__(512, 2) void gemm_mega(
    const unsigned short* __restrict__ Xh, const unsigned short* __restrict__ Xl,
    const unsigned short* __restrict__ Wh, const unsigned short* __restrict__ Wl,
    const unsigned short* __restrict__ Ch, const unsigned short* __restrict__ Cl,
    const unsigned short* __restrict__ Dh, const unsigned short* __restrict__ Dl,
    const float* __restrict__ b_ih, const float* __restrict__ b_hh,
    const float* __restrict__ b_d, const float* __restrict__ cx,
    const float* __restrict__ t, float* __restrict__ out) {
  // 96 KiB total: 2 buffers x (A 256x32 hi/lo + B 128x32 hi/lo)
  __shared__ __align__(16) unsigned short sAh[2][8192];
  __shared__ __align__(16) unsigned short sAl[2][8192];
  __shared__ __align__(16) unsigned short sBh[2][4096];
  __shared__ __align__(16) unsigned short sBl[2][4096];

  // bijective XCD swizzle: 512 wgs = 8 xcd x 64
  const int swz = ((blockIdx.x & 7) << 6) | (blockIdx.x >> 3);
  const int n_blk = swz & 31;
  const int m_blk = swz >> 5;
  const int m0 = m_blk * 256;
  const int n0 = n_blk * 128;  // interleaved-W row offset
  const int h0 = n_blk * 32;   // global h offset of this block

  const int tid = threadIdx.x;
  const int wave = tid >> 6;
  const int lane = tid & 63;
  const int wr = wave >> 1;   // 0..3 (M)
  const int wc = wave & 1;    // 0..1 (N)
  const int srow = lane >> 2;
  const int ssw = (((lane & 3) ^ ((lane >> 3) & 3)) << 3);  // bf16 elems
  const int fm = lane & 15;
  const int fq = lane >> 4;
  const int psw = (fq ^ ((fm >> 1) & 3)) << 3;

#define STAGE1(B_, KT_)                                                        \
  {                                                                            \
    const long gA0 = (long)(m0 + wave * 32 + srow) * 1024 + (KT_) + ssw;       \
    gl_lds16(Ch + gA0, &sAh[B_][(wave * 32) * 32]);                            \
    gl_lds16(Cl + gA0, &sAl[B_][(wave * 32) * 32]);                            \
    const long gA1 = gA0 + 16 * 1024;                                          \
    gl_lds16(Ch + gA1, &sAh[B_][(wave * 32 + 16) * 32]);                       \
    gl_lds16(Cl + gA1, &sAl[B_][(wave * 32 + 16) * 32]);                       \
    if (wave < 4) {                                                            \
      const int rb = (wave & 1) * 16;                                          \
      const long gD = (long)(h0 + rb + srow) * 1024 + (KT_) + ssw;             \
      if (wave & 2) gl_lds16(Dl + gD, &sBl[B_][rb * 32]);                      \
      else          gl_lds16(Dh + gD, &sBh[B_][rb * 32]);                      \
    }                                                                          \
  }

#define STAGE2(B_, KT_)                                                        \
  {                                                                            \
    const long gA0 = (long)(m0 + wave * 32 + srow) * 1536 + (KT_) + ssw;       \
    gl_lds16(Xh + gA0, &sAh[B_][(wave * 32) * 32]);                            \
    gl_lds16(Xl + gA0, &sAl[B_][(wave * 32) * 32]);                            \
    const long gA1 = gA0 + 16 * 1536;                                          \
    gl_lds16(Xh + gA1, &sAh[B_][(wave * 32 + 16) * 32]);                       \
    gl_lds16(Xl + gA1, &sAl[B_][(wave * 32 + 16) * 32]);                       \
    const long gB0 = (long)(n0 + wave * 16 + srow) * 1536 + (KT_) + ssw;       \
    gl_lds16(Wh + gB0, &sBh[B_][(wave * 16) * 32]);                            \
    gl_lds16(Wl + gB0, &sBl[B_][(wave * 16) * 32]);                            \
  }

  // ---------------- phase 1: decomp  dacc = cx @ D^T (K=1024) ----------------
  f32x4 dacc[4];
#pragma unroll
  for (int i = 0; i < 4; ++i) dacc[i] = {0.f, 0.f, 0.f, 0.f};

  STAGE1(0, 0);
#pragma unroll 2
  for (int it = 0; it < 32; ++it) {
    const int b = it & 1;
    if (it < 31) {
      STAGE1(b ^ 1, (it + 1) * 32);
      if (wave < 4) asm volatile("s_waitcnt vmcnt(5)" ::: "memory");
      else          asm volatile("s_waitcnt vmcnt(4)" ::: "memory");
    } else {
      asm volatile("s_waitcnt vmcnt(0)" ::: "memory");
    }
    __builtin_amdgcn_s_barrier();
    // -- P0: read A-half0 + B, MFMA mf{0,1}
    bf16x8 ah01[2], al01[2];
#pragma unroll
    for (int mf = 0; mf < 2; ++mf) {
      const int ao = (wr * 64 + mf * 16 + fm) * 32 + psw;
      ah01[mf] = *(const bf16x8*)&sAh[b][ao];
      al01[mf] = *(const bf16x8*)&sAl[b][ao];
    }
    const int bo = (wc * 16 + fm) * 32 + psw;
    const bf16x8 bh = *(const bf16x8*)&sBh[b][bo];
    const bf16x8 bl = *(const bf16x8*)&sBl[b][bo];
    __builtin_amdgcn_s_setprio(1);
#pragma unroll
    for (int mf = 0; mf < 2; ++mf) {
      dacc[mf] = __builtin_amdgcn_mfma_f32_16x16x32_bf16(ah01[mf], bh, dacc[mf], 0, 0, 0);
      dacc[mf] = __builtin_amdgcn_mfma_f32_16x16x32_bf16(ah01[mf], bl, dacc[mf], 0, 0, 0);
      dacc[mf] = __builtin_amdgcn_mfma_f32_16x16x32_bf16(al01[mf], bh, dacc[mf], 0, 0, 0);
    }
    __builtin_amdgcn_s_setprio(0);
    __builtin_amdgcn_s_barrier();
    // -- P1: read A-half1, MFMA mf{2,3}
    bf16x8 ah23[2], al23[2];
#pragma unroll
    for (int mf = 0; mf < 2; ++mf) {
      const int ao = (wr * 64 + (mf + 2) * 16 + fm) * 32 + psw;
      ah23[mf] = *(const bf16x8*)&sAh[b][ao];
      al23[mf] = *(const bf16x8*)&sAl[b][ao];
    }
    __builtin_amdgcn_s_setprio(1);
#pragma unroll
    for (int mf = 0; mf < 2; ++mf) {
      dacc[mf + 2] = __builtin_amdgcn_mfma_f32_16x16x32_bf16(ah23[mf], bh, dacc[mf + 2], 0, 0, 0);
      dacc[mf + 2] = __builtin_amdgcn_mfma_f32_16x16x32_bf16(ah23[mf], bl, dacc[mf + 2], 0, 0, 0);
      dacc[mf + 2] = __builtin_amdgcn_mfma_f32_16x16x32_bf16(al23[mf], bh, dacc[mf + 2], 0, 0, 0);
    }
    __builtin_amdgcn_s_setprio(0);
    __builtin_amdgcn_s_barrier();
  }

  // ---------------- phase 2: gates  acc = X @ W'^T (K=1536) ----------------
  f32x4 acc[4][4];
#pragma unroll
  for (int i = 0; i < 4; ++i)
#pragma unroll
    for (int j = 0; j < 4; ++j) acc[i][j] = {0.f, 0.f, 0.f, 0.f};

  STAGE2(0, 0);
#pragma unroll 2
  for (int it = 0; it < 48; ++it) {
    const int b = it & 1;
    if (it < 47) {
      STAGE2(b ^ 1, (it + 1) * 32);
      asm volatile("s_waitcnt vmcnt(6)" ::: "memory");
    } else {
      asm volatile("s_waitcnt vmcnt(0)" ::: "memory");
    }
    __builtin_amdgcn_s_barrier();
    // -- P0: read A01 + B01, MFMA quadrant (mf01 x nf01)
    bf16x8 ah01[2], al01[2], bh01[2], bl01[2];
#pragma unroll
    for (int mf = 0; mf < 2; ++mf) {
      const int ao = (wr * 64 + mf * 16 + fm) * 32 + psw;
      ah01[mf] = *(const bf16x8*)&sAh[b][ao];
      al01[mf] = *(const bf16x8*)&sAl[b][ao];
    }
#pragma unroll
    for (int nf = 0; nf < 2; ++nf) {
      const int bo = (wc * 64 + nf * 16 + fm) * 32 + psw;
      bh01[nf] = *(const bf16x8*)&sBh[b][bo];
      bl01[nf] = *(const bf16x8*)&sBl[b][bo];
    }
    __builtin_amdgcn_s_setprio(1);
#pragma unroll
    for (int nf = 0; nf < 2; ++nf)
#pragma unroll
      for (int mf = 0; mf < 2; ++mf) {
        acc[mf][nf] = __builtin_amdgcn_mfma_f32_16x16x32_bf16(ah01[mf], bh01[nf], acc[mf][nf], 0, 0, 0);
        acc[mf][nf] = __builtin_amdgcn_mfma_f32_16x16x32_bf16(ah01[mf], bl01[nf], acc[mf][nf], 0, 0, 0);
        acc[mf][nf] = __builtin_amdgcn_mfma_f32_16x16x32_bf16(al01[mf], bh01[nf], acc[mf][nf], 0, 0, 0);
      }
    __builtin_amdgcn_s_setprio(0);
    __builtin_amdgcn_s_barrier();
    // -- P1: read B23, MFMA quadrant (mf01 x nf23)
    bf16x8 bh23[2], bl23[2];
#pragma unroll
    for (int nf = 0; nf < 2; ++nf) {
      const int bo = (wc * 64 + (nf + 2) * 16 + fm) * 32 + psw;
      bh23[nf] = *(const bf16x8*)&sBh[b][bo];
      bl23[nf] = *(const bf16x8*)&sBl[b][bo];
    }
    __builtin_amdgcn_s_setprio(1);
#pragma unroll
    for (int nf = 0; nf < 2; ++nf)
#pragma unroll
      for (int mf = 0; mf < 2; ++mf) {
        acc[mf][nf + 2] = __builtin_amdgcn_mfma_f32_16x16x32_bf16(ah01[mf], bh23[nf], acc[mf][nf + 2], 0, 0, 0);
        acc[mf][nf + 2] = __builtin_amdgcn_mfma_f32_16x16x32_bf16(ah01[mf], bl23[nf], acc[mf][nf + 2], 0, 0, 0);
        acc[mf][nf + 2] = __builtin_amdgcn_mfma_f32_16x16x32_bf16(al01[mf], bh23[nf], acc[mf][nf + 2], 0, 0, 0);
      }
    __builtin_amdgcn_s_setprio(0);
    __builtin_amdgcn_s_barrier();
    // -- P2: read A23, MFMA quadrant (mf23 x nf23)
    bf16x8 ah23[2], al23[2];
#pragma unroll
    for (int mf = 0; mf < 2; ++mf) {
      const int ao = (wr * 64 + (mf + 2) * 16 + fm) * 32 + psw;
      ah23[mf] = *(const bf16x8*)&sAh[b][ao];
      al23[mf] = *(const bf16x8*)&sAl[b][ao];
    }
    __builtin_amdgcn_s_setprio(1);
#pragma unroll
    for (int nf = 0; nf < 2; ++nf)
#pragma unroll
      for (int mf = 0; mf < 2; ++mf) {
        acc[mf + 2][nf + 2] = __builtin_amdgcn_mfma_f32_16x16x32_bf16(ah23[mf], bh23[nf], acc[mf + 2][nf + 2], 0, 0, 0);
        acc[mf + 2][nf + 2] = __builtin_amdgcn_mfma_f32_16x16x32_bf16(ah23[mf], bl23[nf], acc[mf + 2][nf + 2], 0, 0, 0);
        acc[mf + 2][nf + 2] = __builtin_amdgcn_mfma_f32_16x16x32_bf16(al23[mf], bh23[nf], acc[mf + 2][nf + 2], 0, 0, 0);
      }
    __builtin_amdgcn_s_setprio(0);
    __builtin_amdgcn_s_barrier();
    // -- P3: no reads (operands live), MFMA quadrant (mf23 x nf01)
    __builtin_amdgcn_s_setprio(1);
#pragma unroll
    for (int nf = 0; nf < 2; ++nf)
#pragma unroll
      for (int mf = 0; mf < 2; ++mf) {
        acc[mf + 2][nf] = __builtin_amdgcn_mfma_f32_16x16x32_bf16(ah23[mf], bh01[nf], acc[mf + 2][nf], 0, 0, 0);
        acc[mf + 2][nf] = __builtin_amdgcn_mfma_f32_16x16x32_bf16(ah23[mf], bl01[nf], acc[mf + 2][nf], 0, 0, 0);
        acc[mf + 2][nf] = __builtin_amdgcn_mfma_f32_16x16x32_bf16(al23[mf], bh01[nf], acc[mf + 2][nf], 0, 0, 0);
      }
    __builtin_amdgcn_s_setprio(0);
    __builtin_amdgcn_s_barrier();
  }

  // ---------------- epilogue: full T-LSTM pointwise ----------------
  // thread outputs: m = m0 + wr*64 + mf*16 + fq*4 + r ; h = h0 + wc*16 + fm
  // gate nf of acc[mf][nf][r]: 0=i 1=f 2=g 3=o
  const int h = h0 + wc * 16 + fm;
  const float bi  = b_ih[h]        + b_hh[h];
  const float bff = b_ih[1024 + h] + b_hh[1024 + h];
  const float bg  = b_ih[2048 + h] + b_hh[2048 + h];
  const float bo2 = b_ih[3072 + h] + b_hh[3072 + h];
  const float bd  = b_d[h];
#pragma unroll
  for (int mf = 0; mf < 4; ++mf) {
#pragma unroll
    for (int r = 0; r < 4; ++r) {
      const int m = m0 + wr * 64 + mf * 16 + fq * 4 + r;
      const float tv = t[m];
      const float T = (tv != 0.0f) ? (1.0f / tv) : 0.0f;
      const float cst = tanh_f(dacc[mf][r] + bd);
      const float cadj = cx[(long)m * 1024 + h] + (T - 1.0f) * cst;
      const float ig = sigm_f(acc[mf][0][r] + bi);
      const float fg = sigm_f(acc[mf][1][r] + bff);
      const float cg = tanh_f(acc[mf][2][r] + bg);
      const float og = sigm_f(acc[mf][3][r] + bo2);
      const float cyv = fg * cadj + ig * cg;
      const float hyv = og * tanh_f(cyv);
      out[(long)m * 1024 + h] = hyv;
      out[4096L * 1024 + (long)m * 1024 + h] = cyv;
    }
  }
#undef STAGE1
#undef STAGE2
}

extern "C" void kernel_launch(void* const* d_in, const int* in_sizes, int n_in,
                              void* d_out, int out_size, void* d_ws, size_t ws_size,
                              hipStream_t stream) {
  const float* input = (const float*)d_in[0];
  const float* t     = (const float*)d_in[1];
  const float* hx    = (const float*)d_in[2];
  const float* cx    = (const float*)d_in[3];
  const float* w_ih  = (const float*)d_in[4];
  const float* w_hh  = (const float*)d_in[5];
  const float* b_ih  = (const float*)d_in[6];
  const float* b_hh  = (const float*)d_in[7];
  const float* Wd    = (const float*)d_in[8];
  const float* b_d   = (const float*)d_in[9];

  const long B = 4096, H = 1024, KX = 1536, NG = 4096;

  char* ws = (char*)d_ws;
  unsigned short* Xhi = (unsigned short*)ws; ws += B * KX * 2;
  unsigned short* Xlo = (unsigned short*)ws; ws += B * KX * 2;
  unsigned short* Whi = (unsigned short*)ws; ws += NG * KX * 2;
  unsigned short* Wlo = (unsigned short*)ws; ws += NG * KX * 2;
  unsigned short* Chi = (unsigned short*)ws; ws += B * H * 2;
  unsigned short* Clo = (unsigned short*)ws; ws += B * H * 2;
  unsigned short* Dhi = (unsigned short*)ws; ws += H * H * 2;
  unsigned short* Dlo = (unsigned short*)ws; ws += H * H * 2;

  // 1: hi/lo splits (X, W gate-interleaved at 16-h granularity, cx)
  prep_k<<<12288, 384, 0, stream>>>(input, hx, w_ih, w_hh, cx,
                                    Xhi, Xlo, Whi, Wlo, Chi, Clo);
  // 2: transpose-split W_decomp -> D[h][k]
  transpose_split_k<<<dim3(16, 16), dim3(64, 4), 0, stream>>>(Wd, 1024, Dhi, Dlo);
  // 3: 4-phase pipelined mega GEMM (decomp + gates + full pointwise epilogue)
  gemm_mega<<<512, 512, 0, stream>>>(Xhi, Xlo, Whi, Wlo, Chi, Clo, Dhi, Dlo,
                                     b_ih, b_hh, b_d, cx, t, (float*)d_out);
}

// Round 3
// 339.592 us; speedup vs baseline: 1.1270x; 1.1270x over previous
//
#include <hip/hip_runtime.h>
#include <cstdint>

// ---------------------------------------------------------------------------
// T-LSTM cell, fp32 in/out, split-bf16 MFMA.
// Round 7: revert to R4's proven monolithic schedule (single-buffered 32KB
// LDS, __syncthreads, 1024 blocks -> 3-4 resident blocks/CU provide the
// pipeline overlap via block desync). Change: 4 waves as 2Mx2N (64x64/wave,
// nf=gate via 16-h interleave) instead of 4Mx1N (32x128/wave): per-block-step
// LDS reads drop 80->64 b128 (960->768cy) vs 931cy MFMA. Plus bijective XCD
// swizzle and transpose fused into prep (2 dispatches total).
// ---------------------------------------------------------------------------

typedef __attribute__((ext_vector_type(8))) __bf16 bf16x8;
typedef __attribute__((ext_vector_type(4))) float f32x4;

__device__ __forceinline__ unsigned short f2bf_rn(float f) {
  unsigned int u = __float_as_uint(f);
  unsigned int r = u + 0x7fffu + ((u >> 16) & 1u);
  return (unsigned short)(r >> 16);
}
__device__ __forceinline__ float bf2f(unsigned short h) {
  return __uint_as_float(((unsigned int)h) << 16);
}
__device__ __forceinline__ float sigm_f(float x) {
  return 1.0f / (1.0f + __expf(-x));
}
__device__ __forceinline__ float tanh_f(float x) {
  return 1.0f - 2.0f / (__expf(2.0f * x) + 1.0f);
}
__device__ __forceinline__ void gl_lds16(const void* g, void* l) {
  __builtin_amdgcn_global_load_lds(
      (const __attribute__((address_space(1))) void*)g,
      (__attribute__((address_space(3))) void*)l, 16, 0, 0);
}

// --- prep: split X=[input|hx], W=[w_ih|w_hh] (rows gate-interleaved), cx,
//           and transpose-split W_decomp, all in one dispatch.
// blocks [0,4096): X row m          (384 thr x 4)
// blocks [4096,8192): W source row n -> dest row (h>>4)*64+g*16+(h&15)
// blocks [8192,12288): cx row       (256 thr active)
// blocks [12288,12544): W_decomp 64x64 transpose tiles (384 thr, stride-6 rows)
__global__ __launch_bounds__(384) void prep_k(
    const float* __restrict__ input, const float* __restrict__ hx,
    const float* __restrict__ w_ih, const float* __restrict__ w_hh,
    const float* __restrict__ cx, const float* __restrict__ Wd,
    unsigned short* __restrict__ Xhi, unsigned short* __restrict__ Xlo,
    unsigned short* __restrict__ Whi, unsigned short* __restrict__ Wlo,
    unsigned short* __restrict__ Chi, unsigned short* __restrict__ Clo,
    unsigned short* __restrict__ Dhi, unsigned short* __restrict__ Dlo) {
  const int bid = blockIdx.x;
  if (bid >= 12288) {
    // ---- transpose-split W_decomp [1024,1024] -> D[h][k] = Wd[k][h]
    __shared__ float tile[64][65];
    const int tb = bid - 12288;
    const int bx = (tb & 15) * 64;
    const int by = (tb >> 4) * 64;
    const int tx = threadIdx.x & 63;
    const int ty = threadIdx.x >> 6;  // 0..5
    for (int r = ty; r < 64; r += 6)
      tile[r][tx] = Wd[(long)(by + r) * 1024 + bx + tx];
    __syncthreads();
    for (int r = ty; r < 64; r += 6) {
      float v = tile[tx][r];  // = Wd[by+tx][bx+r]
      unsigned short h = f2bf_rn(v);
      long o = (long)(bx + r) * 1024 + by + tx;
      Dhi[o] = h;
      Dlo[o] = f2bf_rn(v - bf2f(h));
    }
    return;
  }
  const int k = threadIdx.x << 2;
  const float* src;
  unsigned short *hi, *lo;
  if (bid < 4096) {
    const long m = bid;
    src = (k < 512) ? (input + m * 512 + k) : (hx + m * 1024 + (k - 512));
    hi = Xhi + m * 1536 + k;
    lo = Xlo + m * 1536 + k;
  } else if (bid < 8192) {
    const int n = bid - 4096;
    const int g = n >> 10;
    const int h = n & 1023;
    const long nd = ((long)(h >> 4) << 6) | (g << 4) | (h & 15);  // 16-h interleave
    src = (k < 512) ? (w_ih + (long)n * 512 + k) : (w_hh + (long)n * 1024 + (k - 512));
    hi = Whi + nd * 1536 + k;
    lo = Wlo + nd * 1536 + k;
  } else {
    if (k >= 1024) return;
    const long m = bid - 8192;
    src = cx + m * 1024 + k;
    hi = Chi + m * 1024 + k;
    lo = Clo + m * 1024 + k;
  }
  float4 v = *(const float4*)src;
  ushort4 hv, lv;
  hv.x = f2bf_rn(v.x); lv.x = f2bf_rn(v.x - bf2f(hv.x));
  hv.y = f2bf_rn(v.y); lv.y = f2bf_rn(v.y - bf2f(hv.y));
  hv.z = f2bf_rn(v.z); lv.z = f2bf_rn(v.z - bf2f(hv.z));
  hv.w = f2bf_rn(v.w); lv.w = f2bf_rn(v.w - bf2f(hv.w));
  *(ushort4*)hi = hv;
  *(ushort4*)lo = lv;
}

// --- mega kernel: per block (m_blk, n_blk):
//   phase 1: dacc[4] = cx[128m] @ D[32h]^T  (K=1024)
//   phase 2: acc[4][4] = X[128m] @ W'[128n']^T (K=1536); nf == gate
//   epilogue: full T-LSTM pointwise -> hy, cy (direct to out)
// 256 thr, 4 waves 2Mx2N, wave tile 64x64 (4x4 16x16 frags).
// LDS swizzle (R3-verified, 0 conflicts): phys chunk p of row r holds logical
// chunk p^((r>>1)&3); staging lane L fetches logical (L&3)^((L>>3)&3).
__global__ __launch_bounds__(256) void gemm_mega(
    const unsigned short* __restrict__ Xh, const unsigned short* __restrict__ Xl,
    const unsigned short* __restrict__ Wh, const unsigned short* __restrict__ Wl,
    const unsigned short* __restrict__ Ch, const unsigned short* __restrict__ Cl,
    const unsigned short* __restrict__ Dh, const unsigned short* __restrict__ Dl,
    const float* __restrict__ b_ih, const float* __restrict__ b_hh,
    const float* __restrict__ b_d, const float* __restrict__ cx,
    const float* __restrict__ t, float* __restrict__ out) {
  __shared__ __align__(16) unsigned short sAh[128 * 32];
  __shared__ __align__(16) unsigned short sAl[128 * 32];
  __shared__ __align__(16) unsigned short sBh[128 * 32];
  __shared__ __align__(16) unsigned short sBl[128 * 32];

  // bijective XCD swizzle: 1024 wgs = 8 xcd x 128; per XCD 4 m_blks x 32 n_blks
  const int swz = ((blockIdx.x & 7) << 7) | (blockIdx.x >> 3);
  const int n_blk = swz & 31;
  const int m_blk = swz >> 5;
  const int m0 = m_blk * 128;
  const int n0 = n_blk * 128;  // interleaved-W row offset
  const int h0 = n_blk * 32;   // global h offset of this block

  const int tid = threadIdx.x;
  const int wave = tid >> 6;
  const int lane = tid & 63;
  const int wr = wave >> 1;   // 0..1 (M)
  const int wc = wave & 1;    // 0..1 (N)
  const int srow = lane >> 2;
  const int ssw = (((lane & 3) ^ ((lane >> 3) & 3)) << 3);  // bf16 elems
  const int fm = lane & 15;
  const int fq = lane >> 4;
  const int psw = (fq ^ ((fm >> 1) & 3)) << 3;

  // ---------------- phase 1: decomp  dacc = cx @ D^T ----------------
  f32x4 dacc[4];
#pragma unroll
  for (int i = 0; i < 4; ++i) dacc[i] = {0.f, 0.f, 0.f, 0.f};

  for (int kt = 0; kt < 1024; kt += 32) {
#pragma unroll
    for (int r = 0; r < 2; ++r) {
      const int rowb = r * 64 + wave * 16;
      const long gA = (long)(m0 + rowb + srow) * 1024 + kt + ssw;
      gl_lds16(Ch + gA, sAh + rowb * 32);
      gl_lds16(Cl + gA, sAl + rowb * 32);
    }
    {
      const int rb = (wave & 1) * 16;
      const long gD = (long)(h0 + rb + srow) * 1024 + kt + ssw;
      if (wave & 2) gl_lds16(Dl + gD, sBl + rb * 32);
      else          gl_lds16(Dh + gD, sBh + rb * 32);
    }
    __syncthreads();
    bf16x8 ah[4], al[4];
#pragma unroll
    for (int mf = 0; mf < 4; ++mf) {
      const int ao = (wr * 64 + mf * 16 + fm) * 32 + psw;
      ah[mf] = *(const bf16x8*)(sAh + ao);
      al[mf] = *(const bf16x8*)(sAl + ao);
    }
    const int bo = (wc * 16 + fm) * 32 + psw;
    const bf16x8 bh = *(const bf16x8*)(sBh + bo);
    const bf16x8 bl = *(const bf16x8*)(sBl + bo);
#pragma unroll
    for (int mf = 0; mf < 4; ++mf) {
      dacc[mf] = __builtin_amdgcn_mfma_f32_16x16x32_bf16(ah[mf], bh, dacc[mf], 0, 0, 0);
      dacc[mf] = __builtin_amdgcn_mfma_f32_16x16x32_bf16(ah[mf], bl, dacc[mf], 0, 0, 0);
      dacc[mf] = __builtin_amdgcn_mfma_f32_16x16x32_bf16(al[mf], bh, dacc[mf], 0, 0, 0);
    }
    __syncthreads();
  }

  // ---------------- phase 2: gates  acc = X @ W'^T ----------------
  f32x4 acc[4][4];
#pragma unroll
  for (int i = 0; i < 4; ++i)
#pragma unroll
    for (int j = 0; j < 4; ++j) acc[i][j] = {0.f, 0.f, 0.f, 0.f};

  for (int kt = 0; kt < 1536; kt += 32) {
#pragma unroll
    for (int r = 0; r < 2; ++r) {
      const int rowb = r * 64 + wave * 16;
      const long gA = (long)(m0 + rowb + srow) * 1536 + kt + ssw;
      const long gB = (long)(n0 + rowb + srow) * 1536 + kt + ssw;
      gl_lds16(Xh + gA, sAh + rowb * 32);
      gl_lds16(Xl + gA, sAl + rowb * 32);
      gl_lds16(Wh + gB, sBh + rowb * 32);
      gl_lds16(Wl + gB, sBl + rowb * 32);
    }
    __syncthreads();
    bf16x8 ah[4], al[4], bh[4], bl[4];
#pragma unroll
    for (int mf = 0; mf < 4; ++mf) {
      const int ao = (wr * 64 + mf * 16 + fm) * 32 + psw;
      ah[mf] = *(const bf16x8*)(sAh + ao);
      al[mf] = *(const bf16x8*)(sAl + ao);
    }
#pragma unroll
    for (int nf = 0; nf < 4; ++nf) {
      const int bo = (wc * 64 + nf * 16 + fm) * 32 + psw;
      bh[nf] = *(const bf16x8*)(sBh + bo);
      bl[nf] = *(const bf16x8*)(sBl + bo);
    }
#pragma unroll
    for (int nf = 0; nf < 4; ++nf)
#pragma unroll
      for (int mf = 0; mf < 4; ++mf) {
        acc[mf][nf] = __builtin_amdgcn_mfma_f32_16x16x32_bf16(ah[mf], bh[nf], acc[mf][nf], 0, 0, 0);
        acc[mf][nf] = __builtin_amdgcn_mfma_f32_16x16x32_bf16(ah[mf], bl[nf], acc[mf][nf], 0, 0, 0);
        acc[mf][nf] = __builtin_amdgcn_mfma_f32_16x16x32_bf16(al[mf], bh[nf], acc[mf][nf], 0, 0, 0);
      }
    __syncthreads();
  }

  // ---------------- epilogue: full T-LSTM pointwise ----------------
  // thread outputs: m = m0 + wr*64 + mf*16 + fq*4 + r ; h = h0 + wc*16 + fm
  // gate nf of acc[mf][nf][r]: 0=i 1=f 2=g 3=o
  const int h = h0 + wc * 16 + fm;
  const float bi  = b_ih[h]        + b_hh[h];
  const float bff = b_ih[1024 + h] + b_hh[1024 + h];
  const float bg  = b_ih[2048 + h] + b_hh[2048 + h];
  const float bo2 = b_ih[3072 + h] + b_hh[3072 + h];
  const float bd  = b_d[h];
#pragma unroll
  for (int mf = 0; mf < 4; ++mf) {
#pragma unroll
    for (int r = 0; r < 4; ++r) {
      const int m = m0 + wr * 64 + mf * 16 + fq * 4 + r;
      const float tv = t[m];
      const float T = (tv != 0.0f) ? (1.0f / tv) : 0.0f;
      const float cst = tanh_f(dacc[mf][r] + bd);
      const float cadj = cx[(long)m * 1024 + h] + (T - 1.0f) * cst;
      const float ig = sigm_f(acc[mf][0][r] + bi);
      const float fg = sigm_f(acc[mf][1][r] + bff);
      const float cg = tanh_f(acc[mf][2][r] + bg);
      const float og = sigm_f(acc[mf][3][r] + bo2);
      const float cyv = fg * cadj + ig * cg;
      const float hyv = og * tanh_f(cyv);
      out[(long)m * 1024 + h] = hyv;
      out[4096L * 1024 + (long)m * 1024 + h] = cyv;
    }
  }
}

extern "C" void kernel_launch(void* const* d_in, const int* in_sizes, int n_in,
                              void* d_out, int out_size, void* d_ws, size_t ws_size,
                              hipStream_t stream) {
  const float* input = (const float*)d_in[0];
  const float* t     = (const float*)d_in[1];
  const float* hx    = (const float*)d_in[2];
  const float* cx    = (const float*)d_in[3];
  const float* w_ih  = (const float*)d_in[4];
  const float* w_hh  = (const float*)d_in[5];
  const float* b_ih  = (const float*)d_in[6];
  const float* b_hh  = (const float*)d_in[7];
  const float* Wd    = (const float*)d_in[8];
  const float* b_d   = (const float*)d_in[9];

  const long B = 4096, H = 1024, KX = 1536, NG = 4096;

  char* ws = (char*)d_ws;
  unsigned short* Xhi = (unsigned short*)ws; ws += B * KX * 2;
  unsigned short* Xlo = (unsigned short*)ws; ws += B * KX * 2;
  unsigned short* Whi = (unsigned short*)ws; ws += NG * KX * 2;
  unsigned short* Wlo = (unsigned short*)ws; ws += NG * KX * 2;
  unsigned short* Chi = (unsigned short*)ws; ws += B * H * 2;
  unsigned short* Clo = (unsigned short*)ws; ws += B * H * 2;
  unsigned short* Dhi = (unsigned short*)ws; ws += H * H * 2;
  unsigned short* Dlo = (unsigned short*)ws; ws += H * H * 2;

  // 1: hi/lo splits (X, W 16-h gate-interleaved, cx) + W_decomp transpose
  prep_k<<<12544, 384, 0, stream>>>(input, hx, w_ih, w_hh, cx, Wd,
                                    Xhi, Xlo, Whi, Wlo, Chi, Clo, Dhi, Dlo);
  // 2: mega GEMM (decomp + gates + full pointwise epilogue)
  gemm_mega<<<1024, 256, 0, stream>>>(Xhi, Xlo, Whi, Wlo, Chi, Clo, Dhi, Dlo,
                                      b_ih, b_hh, b_d, cx, t, (float*)d_out);
}

// Round 4
// 327.758 us; speedup vs baseline: 1.1677x; 1.0361x over previous
//
#include <hip/hip_runtime.h>
#include <cstdint>

// ---------------------------------------------------------------------------
// T-LSTM cell, fp32 in/out, split-bf16 MFMA.
// Round 8: consolidation. R7 minus the XCD swizzle (R4's natural bid order
// keeps each XCD's 4 W-panels resident in its 4MB L2 -> W fetched once/XCD;
// the m-chunked swizzle thrashed it: FETCH 201->272MB). Plus pointer-walk
// staging: global base pointers hoisted, x4-unrolled inner loop uses
// p + kk*32 (folds into global_load_lds imm offset), pointers advance once
// per 4 steps -> cuts per-step address VALU ~3x (VALUBusy was 31%).
// Geometry unchanged from R7: 128x128 block, 4 waves 2Mx2N (64x64/wave),
// nf==gate via 16-h interleave, single-buffered 32KB LDS, 4 blocks/CU.
// ---------------------------------------------------------------------------

typedef __attribute__((ext_vector_type(8))) __bf16 bf16x8;
typedef __attribute__((ext_vector_type(4))) float f32x4;

__device__ __forceinline__ unsigned short f2bf_rn(float f) {
  unsigned int u = __float_as_uint(f);
  unsigned int r = u + 0x7fffu + ((u >> 16) & 1u);
  return (unsigned short)(r >> 16);
}
__device__ __forceinline__ float bf2f(unsigned short h) {
  return __uint_as_float(((unsigned int)h) << 16);
}
__device__ __forceinline__ float sigm_f(float x) {
  return 1.0f / (1.0f + __expf(-x));
}
__device__ __forceinline__ float tanh_f(float x) {
  return 1.0f - 2.0f / (__expf(2.0f * x) + 1.0f);
}
__device__ __forceinline__ void gl_lds16(const void* g, void* l) {
  __builtin_amdgcn_global_load_lds(
      (const __attribute__((address_space(1))) void*)g,
      (__attribute__((address_space(3))) void*)l, 16, 0, 0);
}

// --- prep: split X=[input|hx], W=[w_ih|w_hh] (rows gate-interleaved), cx,
//           and transpose-split W_decomp, all in one dispatch.
// blocks [0,4096): X row m          (384 thr x 4)
// blocks [4096,8192): W source row n -> dest row (h>>4)*64+g*16+(h&15)
// blocks [8192,12288): cx row       (256 thr active)
// blocks [12288,12544): W_decomp 64x64 transpose tiles (384 thr, stride-6 rows)
__global__ __launch_bounds__(384) void prep_k(
    const float* __restrict__ input, const float* __restrict__ hx,
    const float* __restrict__ w_ih, const float* __restrict__ w_hh,
    const float* __restrict__ cx, const float* __restrict__ Wd,
    unsigned short* __restrict__ Xhi, unsigned short* __restrict__ Xlo,
    unsigned short* __restrict__ Whi, unsigned short* __restrict__ Wlo,
    unsigned short* __restrict__ Chi, unsigned short* __restrict__ Clo,
    unsigned short* __restrict__ Dhi, unsigned short* __restrict__ Dlo) {
  const int bid = blockIdx.x;
  if (bid >= 12288) {
    // ---- transpose-split W_decomp [1024,1024] -> D[h][k] = Wd[k][h]
    __shared__ float tile[64][65];
    const int tb = bid - 12288;
    const int bx = (tb & 15) * 64;
    const int by = (tb >> 4) * 64;
    const int tx = threadIdx.x & 63;
    const int ty = threadIdx.x >> 6;  // 0..5
    for (int r = ty; r < 64; r += 6)
      tile[r][tx] = Wd[(long)(by + r) * 1024 + bx + tx];
    __syncthreads();
    for (int r = ty; r < 64; r += 6) {
      float v = tile[tx][r];  // = Wd[by+tx][bx+r]
      unsigned short h = f2bf_rn(v);
      long o = (long)(bx + r) * 1024 + by + tx;
      Dhi[o] = h;
      Dlo[o] = f2bf_rn(v - bf2f(h));
    }
    return;
  }
  const int k = threadIdx.x << 2;
  const float* src;
  unsigned short *hi, *lo;
  if (bid < 4096) {
    const long m = bid;
    src = (k < 512) ? (input + m * 512 + k) : (hx + m * 1024 + (k - 512));
    hi = Xhi + m * 1536 + k;
    lo = Xlo + m * 1536 + k;
  } else if (bid < 8192) {
    const int n = bid - 4096;
    const int g = n >> 10;
    const int h = n & 1023;
    const long nd = ((long)(h >> 4) << 6) | (g << 4) | (h & 15);  // 16-h interleave
    src = (k < 512) ? (w_ih + (long)n * 512 + k) : (w_hh + (long)n * 1024 + (k - 512));
    hi = Whi + nd * 1536 + k;
    lo = Wlo + nd * 1536 + k;
  } else {
    if (k >= 1024) return;
    const long m = bid - 8192;
    src = cx + m * 1024 + k;
    hi = Chi + m * 1024 + k;
    lo = Clo + m * 1024 + k;
  }
  float4 v = *(const float4*)src;
  ushort4 hv, lv;
  hv.x = f2bf_rn(v.x); lv.x = f2bf_rn(v.x - bf2f(hv.x));
  hv.y = f2bf_rn(v.y); lv.y = f2bf_rn(v.y - bf2f(hv.y));
  hv.z = f2bf_rn(v.z); lv.z = f2bf_rn(v.z - bf2f(hv.z));
  hv.w = f2bf_rn(v.w); lv.w = f2bf_rn(v.w - bf2f(hv.w));
  *(ushort4*)hi = hv;
  *(ushort4*)lo = lv;
}

// --- mega kernel: per block (m_blk, n_blk):
//   phase 1: dacc[4] = cx[128m] @ D[32h]^T  (K=1024)
//   phase 2: acc[4][4] = X[128m] @ W'[128n']^T (K=1536); nf == gate
//   epilogue: full T-LSTM pointwise -> hy, cy (direct to out)
// 256 thr, 4 waves 2Mx2N, wave tile 64x64 (4x4 16x16 frags).
// LDS swizzle (R3-verified, 0 conflicts): phys chunk p of row r holds logical
// chunk p^((r>>1)&3); staging lane L fetches logical (L&3)^((L>>3)&3).
__global__ __launch_bounds__(256) void gemm_mega(
    const unsigned short* __restrict__ Xh, const unsigned short* __restrict__ Xl,
    const unsigned short* __restrict__ Wh, const unsigned short* __restrict__ Wl,
    const unsigned short* __restrict__ Ch, const unsigned short* __restrict__ Cl,
    const unsigned short* __restrict__ Dh, const unsigned short* __restrict__ Dl,
    const float* __restrict__ b_ih, const float* __restrict__ b_hh,
    const float* __restrict__ b_d, const float* __restrict__ cx,
    const float* __restrict__ t, float* __restrict__ out) {
  __shared__ __align__(16) unsigned short sAh[128 * 32];
  __shared__ __align__(16) unsigned short sAl[128 * 32];
  __shared__ __align__(16) unsigned short sBh[128 * 32];
  __shared__ __align__(16) unsigned short sBl[128 * 32];

  // natural order (R4-proven): XCD x serves n_blk in {x, x+8, x+16, x+24}
  // for ALL m -> its 4 W-panels (3.1 MB) stay L2-resident the whole kernel.
  const int n_blk = blockIdx.x & 31;
  const int m_blk = blockIdx.x >> 5;
  const int m0 = m_blk * 128;
  const int n0 = n_blk * 128;  // interleaved-W row offset
  const int h0 = n_blk * 32;   // global h offset of this block

  const int tid = threadIdx.x;
  const int wave = tid >> 6;
  const int lane = tid & 63;
  const int wr = wave >> 1;   // 0..1 (M)
  const int wc = wave & 1;    // 0..1 (N)
  const int srow = lane >> 2;
  const int ssw = (((lane & 3) ^ ((lane >> 3) & 3)) << 3);  // bf16 elems
  const int fm = lane & 15;
  const int fq = lane >> 4;
  const int psw = (fq ^ ((fm >> 1) & 3)) << 3;

  // constant LDS staging destinations (per wave)
  unsigned short* const dA0h = sAh + (wave * 16) * 32;
  unsigned short* const dA0l = sAl + (wave * 16) * 32;
  unsigned short* const dA1h = sAh + (64 + wave * 16) * 32;
  unsigned short* const dA1l = sAl + (64 + wave * 16) * 32;
  unsigned short* const dB0h = sBh + (wave * 16) * 32;
  unsigned short* const dB0l = sBl + (wave * 16) * 32;
  unsigned short* const dB1h = sBh + (64 + wave * 16) * 32;
  unsigned short* const dB1l = sBl + (64 + wave * 16) * 32;

  // ---------------- phase 1: decomp  dacc = cx @ D^T ----------------
  f32x4 dacc[4];
#pragma unroll
  for (int i = 0; i < 4; ++i) dacc[i] = {0.f, 0.f, 0.f, 0.f};

  {
    const long aoff = (long)(m0 + wave * 16 + srow) * 1024 + ssw;
    const unsigned short* pAh0 = Ch + aoff;
    const unsigned short* pAl0 = Cl + aoff;
    const unsigned short* pAh1 = pAh0 + 64 * 1024;
    const unsigned short* pAl1 = pAl0 + 64 * 1024;
    const unsigned short* pD =
        ((wave & 2) ? Dl : Dh) + (long)(h0 + (wave & 1) * 16 + srow) * 1024 + ssw;
    unsigned short* const dD = ((wave & 2) ? sBl : sBh) + ((wave & 1) * 16) * 32;

    for (int kt = 0; kt < 1024; kt += 128) {
#pragma unroll
      for (int kk = 0; kk < 4; ++kk) {
        gl_lds16(pAh0 + kk * 32, dA0h);
        gl_lds16(pAl0 + kk * 32, dA0l);
        gl_lds16(pAh1 + kk * 32, dA1h);
        gl_lds16(pAl1 + kk * 32, dA1l);
        gl_lds16(pD + kk * 32, dD);
        __syncthreads();
        bf16x8 ah[4], al[4];
#pragma unroll
        for (int mf = 0; mf < 4; ++mf) {
          const int ao = (wr * 64 + mf * 16 + fm) * 32 + psw;
          ah[mf] = *(const bf16x8*)(sAh + ao);
          al[mf] = *(const bf16x8*)(sAl + ao);
        }
        const int bo = (wc * 16 + fm) * 32 + psw;
        const bf16x8 bh = *(const bf16x8*)(sBh + bo);
        const bf16x8 bl = *(const bf16x8*)(sBl + bo);
#pragma unroll
        for (int mf = 0; mf < 4; ++mf) {
          dacc[mf] = __builtin_amdgcn_mfma_f32_16x16x32_bf16(ah[mf], bh, dacc[mf], 0, 0, 0);
          dacc[mf] = __builtin_amdgcn_mfma_f32_16x16x32_bf16(ah[mf], bl, dacc[mf], 0, 0, 0);
          dacc[mf] = __builtin_amdgcn_mfma_f32_16x16x32_bf16(al[mf], bh, dacc[mf], 0, 0, 0);
        }
        __syncthreads();
      }
      pAh0 += 128; pAl0 += 128; pAh1 += 128; pAl1 += 128; pD += 128;
    }
  }

  // ---------------- phase 2: gates  acc = X @ W'^T ----------------
  f32x4 acc[4][4];
#pragma unroll
  for (int i = 0; i < 4; ++i)
#pragma unroll
    for (int j = 0; j < 4; ++j) acc[i][j] = {0.f, 0.f, 0.f, 0.f};

  {
    const long aoff = (long)(m0 + wave * 16 + srow) * 1536 + ssw;
    const long boff = (long)(n0 + wave * 16 + srow) * 1536 + ssw;
    const unsigned short* pXh0 = Xh + aoff;
    const unsigned short* pXl0 = Xl + aoff;
    const unsigned short* pXh1 = pXh0 + 64 * 1536;
    const unsigned short* pXl1 = pXl0 + 64 * 1536;
    const unsigned short* pWh0 = Wh + boff;
    const unsigned short* pWl0 = Wl + boff;
    const unsigned short* pWh1 = pWh0 + 64 * 1536;
    const unsigned short* pWl1 = pWl0 + 64 * 1536;

    for (int kt = 0; kt < 1536; kt += 128) {
#pragma unroll
      for (int kk = 0; kk < 4; ++kk) {
        gl_lds16(pXh0 + kk * 32, dA0h);
        gl_lds16(pXl0 + kk * 32, dA0l);
        gl_lds16(pXh1 + kk * 32, dA1h);
        gl_lds16(pXl1 + kk * 32, dA1l);
        gl_lds16(pWh0 + kk * 32, dB0h);
        gl_lds16(pWl0 + kk * 32, dB0l);
        gl_lds16(pWh1 + kk * 32, dB1h);
        gl_lds16(pWl1 + kk * 32, dB1l);
        __syncthreads();
        bf16x8 ah[4], al[4], bh[4], bl[4];
#pragma unroll
        for (int mf = 0; mf < 4; ++mf) {
          const int ao = (wr * 64 + mf * 16 + fm) * 32 + psw;
          ah[mf] = *(const bf16x8*)(sAh + ao);
          al[mf] = *(const bf16x8*)(sAl + ao);
        }
#pragma unroll
        for (int nf = 0; nf < 4; ++nf) {
          const int bo = (wc * 64 + nf * 16 + fm) * 32 + psw;
          bh[nf] = *(const bf16x8*)(sBh + bo);
          bl[nf] = *(const bf16x8*)(sBl + bo);
        }
#pragma unroll
        for (int nf = 0; nf < 4; ++nf)
#pragma unroll
          for (int mf = 0; mf < 4; ++mf) {
            acc[mf][nf] = __builtin_amdgcn_mfma_f32_16x16x32_bf16(ah[mf], bh[nf], acc[mf][nf], 0, 0, 0);
            acc[mf][nf] = __builtin_amdgcn_mfma_f32_16x16x32_bf16(ah[mf], bl[nf], acc[mf][nf], 0, 0, 0);
            acc[mf][nf] = __builtin_amdgcn_mfma_f32_16x16x32_bf16(al[mf], bh[nf], acc[mf][nf], 0, 0, 0);
          }
        __syncthreads();
      }
      pXh0 += 128; pXl0 += 128; pXh1 += 128; pXl1 += 128;
      pWh0 += 128; pWl0 += 128; pWh1 += 128; pWl1 += 128;
    }
  }

  // ---------------- epilogue: full T-LSTM pointwise ----------------
  // thread outputs: m = m0 + wr*64 + mf*16 + fq*4 + r ; h = h0 + wc*16 + fm
  // gate nf of acc[mf][nf][r]: 0=i 1=f 2=g 3=o
  const int h = h0 + wc * 16 + fm;
  const float bi  = b_ih[h]        + b_hh[h];
  const float bff = b_ih[1024 + h] + b_hh[1024 + h];
  const float bg  = b_ih[2048 + h] + b_hh[2048 + h];
  const float bo2 = b_ih[3072 + h] + b_hh[3072 + h];
  const float bd  = b_d[h];
#pragma unroll
  for (int mf = 0; mf < 4; ++mf) {
#pragma unroll
    for (int r = 0; r < 4; ++r) {
      const int m = m0 + wr * 64 + mf * 16 + fq * 4 + r;
      const float tv = t[m];
      const float T = (tv != 0.0f) ? (1.0f / tv) : 0.0f;
      const float cst = tanh_f(dacc[mf][r] + bd);
      const float cadj = cx[(long)m * 1024 + h] + (T - 1.0f) * cst;
      const float ig = sigm_f(acc[mf][0][r] + bi);
      const float fg = sigm_f(acc[mf][1][r] + bff);
      const float cg = tanh_f(acc[mf][2][r] + bg);
      const float og = sigm_f(acc[mf][3][r] + bo2);
      const float cyv = fg * cadj + ig * cg;
      const float hyv = og * tanh_f(cyv);
      out[(long)m * 1024 + h] = hyv;
      out[4096L * 1024 + (long)m * 1024 + h] = cyv;
    }
  }
}

extern "C" void kernel_launch(void* const* d_in, const int* in_sizes, int n_in,
                              void* d_out, int out_size, void* d_ws, size_t ws_size,
                              hipStream_t stream) {
  const float* input = (const float*)d_in[0];
  const float* t     = (const float*)d_in[1];
  const float* hx    = (const float*)d_in[2];
  const float* cx    = (const float*)d_in[3];
  const float* w_ih  = (const float*)d_in[4];
  const float* w_hh  = (const float*)d_in[5];
  const float* b_ih  = (const float*)d_in[6];
  const float* b_hh  = (const float*)d_in[7];
  const float* Wd    = (const float*)d_in[8];
  const float* b_d   = (const float*)d_in[9];

  const long B = 4096, H = 1024, KX = 1536, NG = 4096;

  char* ws = (char*)d_ws;
  unsigned short* Xhi = (unsigned short*)ws; ws += B * KX * 2;
  unsigned short* Xlo = (unsigned short*)ws; ws += B * KX * 2;
  unsigned short* Whi = (unsigned short*)ws; ws += NG * KX * 2;
  unsigned short* Wlo = (unsigned short*)ws; ws += NG * KX * 2;
  unsigned short* Chi = (unsigned short*)ws; ws += B * H * 2;
  unsigned short* Clo = (unsigned short*)ws; ws += B * H * 2;
  unsigned short* Dhi = (unsigned short*)ws; ws += H * H * 2;
  unsigned short* Dlo = (unsigned short*)ws; ws += H * H * 2;

  // 1: hi/lo splits (X, W 16-h gate-interleaved, cx) + W_decomp transpose
  prep_k<<<12544, 384, 0, stream>>>(input, hx, w_ih, w_hh, cx, Wd,
                                    Xhi, Xlo, Whi, Wlo, Chi, Clo, Dhi, Dlo);
  // 2: mega GEMM (decomp + gates + full pointwise epilogue)
  gemm_mega<<<1024, 256, 0, stream>>>(Xhi, Xlo, Whi, Wlo, Chi, Clo, Dhi, Dlo,
                                      b_ih, b_hh, b_d, cx, t, (float*)d_out);
}